// Round 21
// baseline (95.769 us; speedup 1.0000x reference)
//
#include <hip/hip_runtime.h>
#include <hip/hip_bf16.h>

constexpr int B_ = 32, C_ = 256, H_ = 32, W_ = 32, M_ = 1024;
constexpr int NH = 4, DK = 16, DV = 64;
constexpr float EPS = 1e-5f;

using bf16x8 = __bf16 __attribute__((ext_vector_type(8)));
using f32x4  = float __attribute__((ext_vector_type(4)));

struct alignas(8) Bf4 { __bf16 a, b, c, d; };

// ---------------- Kernel 0: W fp32 -> bf16 (once; 36864 elems) -------------
__global__ __launch_bounds__(256) void k_wbf(
    const float* __restrict__ w, __bf16* __restrict__ wbf)
{
    int i = blockIdx.x * 256 + threadIdx.x;          // 9216 float4s
    if (i < 9216) {
        float4 f = reinterpret_cast<const float4*>(w)[i];
        Bf4 o{(__bf16)f.x, (__bf16)f.y, (__bf16)f.z, (__bf16)f.w};
        *reinterpret_cast<Bf4*>(&wbf[i * 4]) = o;
    }
}

// ---------------- Kernel 1: qkv = W @ x via bf16 MFMA, + BN ----------------
// (round-11 version, proven; k_out = RAW logits, softmax folded into k_clam)
__global__ __launch_bounds__(256) void k_qkv(
    const float* __restrict__ x, const __bf16* __restrict__ wbf,
    const float* __restrict__ qg, const float* __restrict__ qb,
    const float* __restrict__ qm, const float* __restrict__ qv,
    const float* __restrict__ vg, const float* __restrict__ vb,
    const float* __restrict__ vm, const float* __restrict__ vv,
    float* __restrict__ q_out, float* __restrict__ k_out,
    float* __restrict__ v_out)
{
    __shared__ __bf16 xT[64 * 72];                 // 9 KB
    __shared__ __align__(16) float ostage[64 * 68]; // 17 KB (reused per pass)
    __shared__ __align__(16) float inv_s[144];
    __shared__ __align__(16) float add_s[144];

    const int b    = blockIdx.x >> 4;
    const int m0   = (blockIdx.x & 15) * 64;
    const int tid  = threadIdx.x;
    const int wv   = tid >> 6;
    const int lane = tid & 63;
    const int col  = lane & 15;
    const int rowg = lane >> 4;

    if (tid < 144) {
        float iv = 1.f, ad = 0.f;
        if (tid < 64)       { iv = qg[tid] * rsqrtf(qv[tid] + EPS); ad = qb[tid] - qm[tid] * iv; }
        else if (tid >= 80) { int d = tid - 80; iv = vg[d] * rsqrtf(vv[d] + EPS); ad = vb[d] - vm[d] * iv; }
        inv_s[tid] = iv; add_s[tid] = ad;
    }

    f32x4 acc[9];
#pragma unroll
    for (int j = 0; j < 9; j++) acc[j] = (f32x4){0.f, 0.f, 0.f, 0.f};

    for (int c0 = 0; c0 < C_; c0 += 64) {
        __syncthreads();
#pragma unroll
        for (int i = 0; i < 4; i++) {
            int flat = tid + 256 * i;
            int m = flat & 63, c4 = flat >> 6;
            const float* xp = &x[((size_t)b * C_ + c0 + c4 * 4) * M_ + m0 + m];
            float f0 = xp[0], f1 = xp[M_], f2 = xp[2 * M_], f3 = xp[3 * M_];
            Bf4 o{(__bf16)f0, (__bf16)f1, (__bf16)f2, (__bf16)f3};
            *reinterpret_cast<Bf4*>(&xT[m * 72 + c4 * 4]) = o;
        }
        __syncthreads();
#pragma unroll
        for (int ks = 0; ks < 2; ks++) {
            const int cl = ks * 32 + rowg * 8;
            bf16x8 bf = *reinterpret_cast<const bf16x8*>(
                &xT[(16 * wv + col) * 72 + cl]);
#pragma unroll
            for (int j = 0; j < 9; j++) {
                bf16x8 af = *reinterpret_cast<const bf16x8*>(
                    &wbf[(size_t)(16 * j + col) * C_ + c0 + cl]);
                acc[j] = __builtin_amdgcn_mfma_f32_16x16x32_bf16(af, bf, acc[j], 0, 0, 0);
            }
        }
    }

    const int mloc = 16 * wv + col;

    __syncthreads();
#pragma unroll
    for (int j = 0; j < 4; j++)
        *reinterpret_cast<f32x4*>(&ostage[mloc * 68 + 16 * j + rowg * 4]) = acc[j];
    __syncthreads();
#pragma unroll
    for (int i = 0; i < 4; i++) {
        int fl = tid + 256 * i;
        int m = fl >> 4, oc4 = (fl & 15) * 4;
        float4 vr = *reinterpret_cast<const float4*>(&ostage[m * 68 + oc4]);
        float4 iv = *reinterpret_cast<const float4*>(&inv_s[oc4]);
        float4 ad = *reinterpret_cast<const float4*>(&add_s[oc4]);
        float4 rs{vr.x * iv.x + ad.x, vr.y * iv.y + ad.y,
                  vr.z * iv.z + ad.z, vr.w * iv.w + ad.w};
        *reinterpret_cast<float4*>(&q_out[((size_t)b * M_ + m0 + m) * 64 + oc4]) = rs;
    }

    __syncthreads();
#pragma unroll
    for (int r = 0; r < 4; r++)
        ostage[(rowg * 4 + r) * 68 + mloc] = acc[4][r];
    __syncthreads();
    {
        int kk = tid >> 4, m4 = (tid & 15) * 4;
        float4 vr = *reinterpret_cast<const float4*>(&ostage[kk * 68 + m4]);
        *reinterpret_cast<float4*>(&k_out[((size_t)b * DK + kk) * M_ + m0 + m4]) = vr;
    }

    __syncthreads();
#pragma unroll
    for (int j = 5; j < 9; j++)
        *reinterpret_cast<f32x4*>(&ostage[mloc * 68 + 16 * (j - 5) + rowg * 4]) = acc[j];
    __syncthreads();
#pragma unroll
    for (int i = 0; i < 4; i++) {
        int fl = tid + 256 * i;
        int m = fl >> 4, oc4 = (fl & 15) * 4;
        float4 vr = *reinterpret_cast<const float4*>(&ostage[m * 68 + oc4]);
        float4 iv = *reinterpret_cast<const float4*>(&inv_s[80 + oc4]);
        float4 ad = *reinterpret_cast<const float4*>(&add_s[80 + oc4]);
        float4 rs{vr.x * iv.x + ad.x, vr.y * iv.y + ad.y,
                  vr.z * iv.z + ad.z, vr.w * iv.w + ad.w};
        *reinterpret_cast<float4*>(&v_out[((size_t)b * M_ + m0 + m) * 64 + oc4]) = rs;
    }
}

// ---------------- Kernel 3: UNNORMALIZED content_lam + partition Z ---------
// r21: softmax folded in.  A[b,k,vd] = sum_m exp(klog)*v ;  Z[b,k] = sum_m exp.
// Normalization (A/Z) applied in k_fuse's cl_s staging (256 divides/block).
// No max-subtraction needed: k logits ~ N(0,1), max ~4.5 -> exp <= ~90, fp32-safe.
__global__ __launch_bounds__(256) void k_clam(
    const float* __restrict__ klog, const float* __restrict__ vbn,
    float* __restrict__ A, float* __restrict__ Z)
{
    const int b   = blockIdx.x >> 4;
    const int m0  = (blockIdx.x & 15) * 64;
    const int tid = threadIdx.x;
    const int vd  = tid & 63;
    const int kq  = tid >> 6;
    float acc[4] = {0.f, 0.f, 0.f, 0.f};
    float zac[4] = {0.f, 0.f, 0.f, 0.f};
    for (int mi = 0; mi < 64; mi++) {
        const int m = m0 + mi;
        const float vvv = vbn[(b * M_ + m) * DV + vd];
#pragma unroll
        for (int j = 0; j < 4; j++) {
            const float e = __expf(klog[(b * DK + kq + 4 * j) * M_ + m]);
            zac[j] += e;
            acc[j] = fmaf(e, vvv, acc[j]);
        }
    }
#pragma unroll
    for (int j = 0; j < 4; j++) {
        atomicAdd(&A[(b * DK + kq + 4 * j) * DV + vd], acc[j]);
        if (vd == 0) atomicAdd(&Z[b * DK + kq + 4 * j], zac[j]);
    }
}

// ---------------- Kernel 4: fused s-compute + pos + content ----------------
// (round-16 version; r21 delta: cl_s staging divides A by Z.  Otherwise frozen.)
__global__ __launch_bounds__(512) void k_fuse(
    const float* __restrict__ vbn, const float* __restrict__ qbn,
    const float* __restrict__ clam, const float* __restrict__ Z,
    const float* __restrict__ lw, const float* __restrict__ lb,
    float* __restrict__ out)
{
    __shared__ float qs[32][68];           // 8.7 KB
    __shared__ float lws[16 * 52];         // 3.3 KB (taps 49..51 = 0)
    __shared__ float s_s[32 * 208];        // 26.6 KB  [px][tap*4+n]
    __shared__ float ostage[64][132];      // 33.8 KB
    __shared__ float cl_s[16 * 64];        // 4 KB
    __shared__ float lb_s[16];

    const int b   = blockIdx.x >> 4;
    const int rt  = blockIdx.x & 15;
    const int h0  = rt * 2;
    const int tid = threadIdx.x;

    for (int i = tid; i < 832; i += 512) {
        int k = i / 52, t = i % 52;
        lws[i] = (t < 49) ? lw[k * 49 + t] : 0.f;
    }
    if (tid < 256) {
        float4 a = *reinterpret_cast<const float4*>(&clam[b * DK * DV + tid * 4]);
        float zi = 1.f / Z[b * DK + (tid >> 4)];
        float4 r{a.x * zi, a.y * zi, a.z * zi, a.w * zi};
        *reinterpret_cast<float4*>(&cl_s[tid * 4]) = r;
    }
    if (tid < 16) lb_s[tid] = lb[tid];

    const int vd  = tid & 63;
    const int pg  = tid >> 6;
    const int px0 = pg * 4;
    const float* vb_b = vbn + (size_t)b * M_ * DV + vd;

    const int qm_ = tid >> 4, qc4 = (tid & 15) * 4;   // q staging coords
    float4 qreg = *reinterpret_cast<const float4*>(
        &qbn[((size_t)b * M_ + h0 * W_ + qm_) * 64 + qc4]);

    for (int grp = 0; grp < 2; grp++) {
        const int mrow = (h0 + grp) * W_;
        // 1) write prefetched q row tile
        *reinterpret_cast<float4*>(&qs[qm_][qc4]) = qreg;
        __syncthreads();               // qs (and lws/cl_s on iter 0) ready

        // 2) s_s[m][t][n] = sum_k qs[m][n*16+k] * lws[k][t]
        if (tid < 416) {
            const int m  = tid / 13;
            const int t4 = (tid % 13) * 4;
            f32x4 a0 = {0.f,0.f,0.f,0.f}, a1 = a0, a2 = a0, a3 = a0;
#pragma unroll
            for (int k = 0; k < 16; k++) {
                float4 lw4 = *reinterpret_cast<const float4*>(&lws[k * 52 + t4]);
                float q0 = qs[m][k],      q1 = qs[m][16 + k];
                float q2 = qs[m][32 + k], q3 = qs[m][48 + k];
                a0[0] = fmaf(q0, lw4.x, a0[0]); a0[1] = fmaf(q1, lw4.x, a0[1]);
                a0[2] = fmaf(q2, lw4.x, a0[2]); a0[3] = fmaf(q3, lw4.x, a0[3]);
                a1[0] = fmaf(q0, lw4.y, a1[0]); a1[1] = fmaf(q1, lw4.y, a1[1]);
                a1[2] = fmaf(q2, lw4.y, a1[2]); a1[3] = fmaf(q3, lw4.y, a1[3]);
                a2[0] = fmaf(q0, lw4.z, a2[0]); a2[1] = fmaf(q1, lw4.z, a2[1]);
                a2[2] = fmaf(q2, lw4.z, a2[2]); a2[3] = fmaf(q3, lw4.z, a2[3]);
                a3[0] = fmaf(q0, lw4.w, a3[0]); a3[1] = fmaf(q1, lw4.w, a3[1]);
                a3[2] = fmaf(q2, lw4.w, a3[2]); a3[3] = fmaf(q3, lw4.w, a3[3]);
            }
            float* sp = &s_s[m * 208 + t4 * 4];
            *reinterpret_cast<f32x4*>(sp)      = a0;
            *reinterpret_cast<f32x4*>(sp + 4)  = a1;
            *reinterpret_cast<f32x4*>(sp + 8)  = a2;
            *reinterpret_cast<f32x4*>(sp + 12) = a3;
        }
        __syncthreads();               // s_s ready

        // (c) prefetch next grp's q while pos path runs
        if (grp == 0)
            qreg = *reinterpret_cast<const float4*>(
                &qbn[((size_t)b * M_ + (h0 + 1) * W_ + qm_) * 64 + qc4]);

        // 3) position path: v direct from global, double-buffered (vrC/vrN)
        float po[4][4];
#pragma unroll
        for (int ip = 0; ip < 4; ip++)
#pragma unroll
            for (int n = 0; n < 4; n++) po[ip][n] = 0.f;

        float vrC[10], vrN[10];
        {
            const int gr = h0 + grp - 3;           // dy = 0 row
            if (gr >= 0 && gr < H_) {
#pragma unroll
                for (int j = 0; j < 10; j++) {
                    const int colc = px0 - 3 + j;
                    vrC[j] = (colc >= 0 && colc < W_)
                           ? vb_b[(size_t)(gr * W_ + colc) * DV] : 0.f;
                }
            } else {
#pragma unroll
                for (int j = 0; j < 10; j++) vrC[j] = 0.f;
            }
        }
#pragma unroll 1
        for (int dy = 0; dy < 7; dy++) {
            // issue next row's loads first (covered by this row's FMAs)
            const int grn = h0 + grp - 2 + dy;     // dy+1 row
            if (dy < 6 && grn >= 0 && grn < H_) {
#pragma unroll
                for (int j = 0; j < 10; j++) {
                    const int colc = px0 - 3 + j;
                    vrN[j] = (colc >= 0 && colc < W_)
                           ? vb_b[(size_t)(grn * W_ + colc) * DV] : 0.f;
                }
            } else {
#pragma unroll
                for (int j = 0; j < 10; j++) vrN[j] = 0.f;
            }
#pragma unroll
            for (int dx = 0; dx < 7; dx++) {
                const int tap = dy * 7 + dx;
#pragma unroll
                for (int ip = 0; ip < 4; ip++) {
                    float4 s4 = *reinterpret_cast<const float4*>(
                        &s_s[(px0 + ip) * 208 + tap * 4]);
                    const float vv = vrC[ip + dx];
                    po[ip][0] = fmaf(vv, s4.x, po[ip][0]);
                    po[ip][1] = fmaf(vv, s4.y, po[ip][1]);
                    po[ip][2] = fmaf(vv, s4.z, po[ip][2]);
                    po[ip][3] = fmaf(vv, s4.w, po[ip][3]);
                }
            }
#pragma unroll
            for (int j = 0; j < 10; j++) vrC[j] = vrN[j];
        }

        // 4) epilogue: lamv hoisted (ip-invariant), content q from LDS
        float lamv[16];
#pragma unroll
        for (int k = 0; k < 16; k++)
            lamv[k] = cl_s[k * DV + vd] + lb_s[k];
#pragma unroll
        for (int ip = 0; ip < 4; ip++) {
            const int p = px0 + ip;
            float4 ov;
            float* ovp = reinterpret_cast<float*>(&ov);
#pragma unroll
            for (int n = 0; n < 4; n++) {
                const float4* q4 = reinterpret_cast<const float4*>(&qs[p][n * 16]);
                float4 qa = q4[0], qb4 = q4[1], qc = q4[2], qd = q4[3];
                ovp[n] = po[ip][n]
                       + qa.x * lamv[0] + qa.y * lamv[1] + qa.z * lamv[2] + qa.w * lamv[3]
                       + qb4.x * lamv[4] + qb4.y * lamv[5] + qb4.z * lamv[6] + qb4.w * lamv[7]
                       + qc.x * lamv[8] + qc.y * lamv[9] + qc.z * lamv[10] + qc.w * lamv[11]
                       + qd.x * lamv[12] + qd.y * lamv[13] + qd.z * lamv[14] + qd.w * lamv[15];
            }
            *reinterpret_cast<float4*>(&ostage[vd][p * 4]) = ov;
        }
        __syncthreads();
        // flush this row: 2048 float4, lanes consecutive -> coalesced
        {
            const int mrow4 = mrow * 4;
            for (int i4 = tid; i4 < 2048; i4 += 512) {
                const int vdw  = i4 >> 5;
                const int off4 = (i4 & 31) * 4;
                float4 val = *reinterpret_cast<const float4*>(&ostage[vdw][off4]);
                *reinterpret_cast<float4*>(
                    out + (size_t)b * (C_ * M_) + (size_t)vdw * 4096 + mrow4 + off4) = val;
            }
        }
        __syncthreads();
    }
}

extern "C" void kernel_launch(void* const* d_in, const int* in_sizes, int n_in,
                              void* d_out, int out_size, void* d_ws, size_t ws_size,
                              hipStream_t stream)
{
    (void)in_sizes; (void)n_in; (void)out_size; (void)ws_size;
    const float* x   = (const float*)d_in[0];
    const float* w   = (const float*)d_in[1];
    const float* qg  = (const float*)d_in[2];
    const float* qb  = (const float*)d_in[3];
    const float* qm  = (const float*)d_in[4];
    const float* qvr = (const float*)d_in[5];
    const float* vg  = (const float*)d_in[6];
    const float* vb  = (const float*)d_in[7];
    const float* vm  = (const float*)d_in[8];
    const float* vvr = (const float*)d_in[9];
    const float* lw  = (const float*)d_in[10];
    const float* lb  = (const float*)d_in[11];
    float* out = (float*)d_out;

    float* ws   = (float*)d_ws;
    float* q_bn = ws;                        // [b][m][n][k]  2,097,152 f
    float* v_bn = ws + 2097152;              // [b][m][vd]    2,097,152 f
    float* k_bf = ws + 4194304;              // [b][k][m]       524,288 f (raw logits)
    float* clam = ws + 4718592;              // [b][k][vd]       32,768 f (unnorm A)
    float* zden = ws + 4751360;              // [b][k]              512 f
    __bf16* wbf = (__bf16*)(ws + 4751872);   // 36,864 bf16

    hipMemsetAsync(clam, 0, (32768 + 512) * sizeof(float), stream);
    hipLaunchKernelGGL(k_wbf, dim3(36), dim3(256), 0, stream, w, wbf);
    hipLaunchKernelGGL(k_qkv, dim3(512), dim3(256), 0, stream,
                       x, wbf, qg, qb, qm, qvr, vg, vb, vm, vvr, q_bn, k_bf, v_bn);
    hipLaunchKernelGGL(k_clam, dim3(512), dim3(256), 0, stream, k_bf, v_bn, clam, zden);
    hipLaunchKernelGGL(k_fuse, dim3(512), dim3(512), 0, stream,
                       v_bn, q_bn, clam, zden, lw, lb, out);
}

// Round 22
// 91.101 us; speedup vs baseline: 1.0512x; 1.0512x over previous
//
#include <hip/hip_runtime.h>
#include <hip/hip_bf16.h>

constexpr int B_ = 32, C_ = 256, H_ = 32, W_ = 32, M_ = 1024;
constexpr int NH = 4, DK = 16, DV = 64;
constexpr float EPS = 1e-5f;

using bf16x8 = __bf16 __attribute__((ext_vector_type(8)));
using f32x4  = float __attribute__((ext_vector_type(4)));

struct alignas(8) Bf4 { __bf16 a, b, c, d; };

// ---------------- Kernel 0: W fp32 -> bf16 (once; 36864 elems) -------------
__global__ __launch_bounds__(256) void k_wbf(
    const float* __restrict__ w, __bf16* __restrict__ wbf)
{
    int i = blockIdx.x * 256 + threadIdx.x;          // 9216 float4s
    if (i < 9216) {
        float4 f = reinterpret_cast<const float4*>(w)[i];
        Bf4 o{(__bf16)f.x, (__bf16)f.y, (__bf16)f.z, (__bf16)f.w};
        *reinterpret_cast<Bf4*>(&wbf[i * 4]) = o;
    }
}

// ---------------- Kernel 1: qkv = W @ x via bf16 MFMA, + BN ----------------
// (round-11 version, proven)
__global__ __launch_bounds__(256) void k_qkv(
    const float* __restrict__ x, const __bf16* __restrict__ wbf,
    const float* __restrict__ qg, const float* __restrict__ qb,
    const float* __restrict__ qm, const float* __restrict__ qv,
    const float* __restrict__ vg, const float* __restrict__ vb,
    const float* __restrict__ vm, const float* __restrict__ vv,
    float* __restrict__ q_out, float* __restrict__ k_out,
    float* __restrict__ v_out)
{
    __shared__ __bf16 xT[64 * 72];                 // 9 KB
    __shared__ __align__(16) float ostage[64 * 68]; // 17 KB (reused per pass)
    __shared__ __align__(16) float inv_s[144];
    __shared__ __align__(16) float add_s[144];

    const int b    = blockIdx.x >> 4;
    const int m0   = (blockIdx.x & 15) * 64;
    const int tid  = threadIdx.x;
    const int wv   = tid >> 6;
    const int lane = tid & 63;
    const int col  = lane & 15;
    const int rowg = lane >> 4;

    if (tid < 144) {
        float iv = 1.f, ad = 0.f;
        if (tid < 64)       { iv = qg[tid] * rsqrtf(qv[tid] + EPS); ad = qb[tid] - qm[tid] * iv; }
        else if (tid >= 80) { int d = tid - 80; iv = vg[d] * rsqrtf(vv[d] + EPS); ad = vb[d] - vm[d] * iv; }
        inv_s[tid] = iv; add_s[tid] = ad;
    }

    f32x4 acc[9];
#pragma unroll
    for (int j = 0; j < 9; j++) acc[j] = (f32x4){0.f, 0.f, 0.f, 0.f};

    for (int c0 = 0; c0 < C_; c0 += 64) {
        __syncthreads();
#pragma unroll
        for (int i = 0; i < 4; i++) {
            int flat = tid + 256 * i;
            int m = flat & 63, c4 = flat >> 6;
            const float* xp = &x[((size_t)b * C_ + c0 + c4 * 4) * M_ + m0 + m];
            float f0 = xp[0], f1 = xp[M_], f2 = xp[2 * M_], f3 = xp[3 * M_];
            Bf4 o{(__bf16)f0, (__bf16)f1, (__bf16)f2, (__bf16)f3};
            *reinterpret_cast<Bf4*>(&xT[m * 72 + c4 * 4]) = o;
        }
        __syncthreads();
#pragma unroll
        for (int ks = 0; ks < 2; ks++) {
            const int cl = ks * 32 + rowg * 8;
            bf16x8 bf = *reinterpret_cast<const bf16x8*>(
                &xT[(16 * wv + col) * 72 + cl]);
#pragma unroll
            for (int j = 0; j < 9; j++) {
                bf16x8 af = *reinterpret_cast<const bf16x8*>(
                    &wbf[(size_t)(16 * j + col) * C_ + c0 + cl]);
                acc[j] = __builtin_amdgcn_mfma_f32_16x16x32_bf16(af, bf, acc[j], 0, 0, 0);
            }
        }
    }

    const int mloc = 16 * wv + col;

    __syncthreads();
#pragma unroll
    for (int j = 0; j < 4; j++)
        *reinterpret_cast<f32x4*>(&ostage[mloc * 68 + 16 * j + rowg * 4]) = acc[j];
    __syncthreads();
#pragma unroll
    for (int i = 0; i < 4; i++) {
        int fl = tid + 256 * i;
        int m = fl >> 4, oc4 = (fl & 15) * 4;
        float4 vr = *reinterpret_cast<const float4*>(&ostage[m * 68 + oc4]);
        float4 iv = *reinterpret_cast<const float4*>(&inv_s[oc4]);
        float4 ad = *reinterpret_cast<const float4*>(&add_s[oc4]);
        float4 rs{vr.x * iv.x + ad.x, vr.y * iv.y + ad.y,
                  vr.z * iv.z + ad.z, vr.w * iv.w + ad.w};
        *reinterpret_cast<float4*>(&q_out[((size_t)b * M_ + m0 + m) * 64 + oc4]) = rs;
    }

    __syncthreads();
#pragma unroll
    for (int r = 0; r < 4; r++)
        ostage[(rowg * 4 + r) * 68 + mloc] = acc[4][r];
    __syncthreads();
    {
        int kk = tid >> 4, m4 = (tid & 15) * 4;
        float4 vr = *reinterpret_cast<const float4*>(&ostage[kk * 68 + m4]);
        *reinterpret_cast<float4*>(&k_out[((size_t)b * DK + kk) * M_ + m0 + m4]) = vr;
    }

    __syncthreads();
#pragma unroll
    for (int j = 5; j < 9; j++)
        *reinterpret_cast<f32x4*>(&ostage[mloc * 68 + 16 * (j - 5) + rowg * 4]) = acc[j];
    __syncthreads();
#pragma unroll
    for (int i = 0; i < 4; i++) {
        int fl = tid + 256 * i;
        int m = fl >> 4, oc4 = (fl & 15) * 4;
        float4 vr = *reinterpret_cast<const float4*>(&ostage[m * 68 + oc4]);
        float4 iv = *reinterpret_cast<const float4*>(&inv_s[80 + oc4]);
        float4 ad = *reinterpret_cast<const float4*>(&add_s[80 + oc4]);
        float4 rs{vr.x * iv.x + ad.x, vr.y * iv.y + ad.y,
                  vr.z * iv.z + ad.z, vr.w * iv.w + ad.w};
        *reinterpret_cast<float4*>(&v_out[((size_t)b * M_ + m0 + m) * 64 + oc4]) = rs;
    }
}

// ---------------- Kernel 2: softmax over M per (b,k) row, in place ---------
// (r17 float4 version, proven)
__global__ __launch_bounds__(256) void k_softmax(float* __restrict__ kl)
{
    float4* p4 = reinterpret_cast<float4*>(kl + (size_t)blockIdx.x * M_);
    const int tid = threadIdx.x;
    float4 v = p4[tid];
    float mx = fmaxf(fmaxf(v.x, v.y), fmaxf(v.z, v.w));
#pragma unroll
    for (int off = 32; off >= 1; off >>= 1) mx = fmaxf(mx, __shfl_xor(mx, off));
    __shared__ float red[8];
    if ((tid & 63) == 0) red[tid >> 6] = mx;
    __syncthreads();
    mx = fmaxf(fmaxf(red[0], red[1]), fmaxf(red[2], red[3]));
    v.x = __expf(v.x - mx); v.y = __expf(v.y - mx);
    v.z = __expf(v.z - mx); v.w = __expf(v.w - mx);
    float s = v.x + v.y + v.z + v.w;
#pragma unroll
    for (int off = 32; off >= 1; off >>= 1) s += __shfl_xor(s, off);
    if ((tid & 63) == 0) red[4 + (tid >> 6)] = s;
    __syncthreads();
    s = red[4] + red[5] + red[6] + red[7];
    float inv = 1.f / s;
    v.x *= inv; v.y *= inv; v.z *= inv; v.w *= inv;
    p4[tid] = v;
}

// ---------------- Kernel 3: content_lam[b,k,vd] = sum_m ksm * v ------------
// (r17 grid-512 version, proven)
__global__ __launch_bounds__(256) void k_clam(
    const float* __restrict__ ksm, const float* __restrict__ vbn,
    float* __restrict__ clam)
{
    const int b   = blockIdx.x >> 4;
    const int m0  = (blockIdx.x & 15) * 64;
    const int tid = threadIdx.x;
    const int vd  = tid & 63;
    const int kq  = tid >> 6;
    float acc[4] = {0.f, 0.f, 0.f, 0.f};
    for (int mi = 0; mi < 64; mi++) {
        const int m = m0 + mi;
        const float vvv = vbn[(b * M_ + m) * DV + vd];
#pragma unroll
        for (int j = 0; j < 4; j++)
            acc[j] = fmaf(ksm[(b * DK + kq + 4 * j) * M_ + m], vvv, acc[j]);
    }
#pragma unroll
    for (int j = 0; j < 4; j++)
        atomicAdd(&clam[(b * DK + kq + 4 * j) * DV + vd], acc[j]);
}

// ---------------- Kernel 4: fused s-compute + pos + content ----------------
// (round-16 version, byte-identical: proven 48.4-48.6 us; frozen)
__global__ __launch_bounds__(512) void k_fuse(
    const float* __restrict__ vbn, const float* __restrict__ qbn,
    const float* __restrict__ clam, const float* __restrict__ lw,
    const float* __restrict__ lb, float* __restrict__ out)
{
    __shared__ float qs[32][68];           // 8.7 KB
    __shared__ float lws[16 * 52];         // 3.3 KB (taps 49..51 = 0)
    __shared__ float s_s[32 * 208];        // 26.6 KB  [px][tap*4+n]
    __shared__ float ostage[64][132];      // 33.8 KB
    __shared__ float cl_s[16 * 64];        // 4 KB
    __shared__ float lb_s[16];

    const int b   = blockIdx.x >> 4;
    const int rt  = blockIdx.x & 15;
    const int h0  = rt * 2;
    const int tid = threadIdx.x;

    for (int i = tid; i < 832; i += 512) {
        int k = i / 52, t = i % 52;
        lws[i] = (t < 49) ? lw[k * 49 + t] : 0.f;
    }
    if (tid < 256)
        *reinterpret_cast<float4*>(&cl_s[tid * 4]) =
            *reinterpret_cast<const float4*>(&clam[b * DK * DV + tid * 4]);
    if (tid < 16) lb_s[tid] = lb[tid];

    const int vd  = tid & 63;
    const int pg  = tid >> 6;
    const int px0 = pg * 4;
    const float* vb_b = vbn + (size_t)b * M_ * DV + vd;

    const int qm_ = tid >> 4, qc4 = (tid & 15) * 4;   // q staging coords
    float4 qreg = *reinterpret_cast<const float4*>(
        &qbn[((size_t)b * M_ + h0 * W_ + qm_) * 64 + qc4]);

    for (int grp = 0; grp < 2; grp++) {
        const int mrow = (h0 + grp) * W_;
        // 1) write prefetched q row tile
        *reinterpret_cast<float4*>(&qs[qm_][qc4]) = qreg;
        __syncthreads();               // qs (and lws/cl_s on iter 0) ready

        // 2) s_s[m][t][n] = sum_k qs[m][n*16+k] * lws[k][t]
        if (tid < 416) {
            const int m  = tid / 13;
            const int t4 = (tid % 13) * 4;
            f32x4 a0 = {0.f,0.f,0.f,0.f}, a1 = a0, a2 = a0, a3 = a0;
#pragma unroll
            for (int k = 0; k < 16; k++) {
                float4 lw4 = *reinterpret_cast<const float4*>(&lws[k * 52 + t4]);
                float q0 = qs[m][k],      q1 = qs[m][16 + k];
                float q2 = qs[m][32 + k], q3 = qs[m][48 + k];
                a0[0] = fmaf(q0, lw4.x, a0[0]); a0[1] = fmaf(q1, lw4.x, a0[1]);
                a0[2] = fmaf(q2, lw4.x, a0[2]); a0[3] = fmaf(q3, lw4.x, a0[3]);
                a1[0] = fmaf(q0, lw4.y, a1[0]); a1[1] = fmaf(q1, lw4.y, a1[1]);
                a1[2] = fmaf(q2, lw4.y, a1[2]); a1[3] = fmaf(q3, lw4.y, a1[3]);
                a2[0] = fmaf(q0, lw4.z, a2[0]); a2[1] = fmaf(q1, lw4.z, a2[1]);
                a2[2] = fmaf(q2, lw4.z, a2[2]); a2[3] = fmaf(q3, lw4.z, a2[3]);
                a3[0] = fmaf(q0, lw4.w, a3[0]); a3[1] = fmaf(q1, lw4.w, a3[1]);
                a3[2] = fmaf(q2, lw4.w, a3[2]); a3[3] = fmaf(q3, lw4.w, a3[3]);
            }
            float* sp = &s_s[m * 208 + t4 * 4];
            *reinterpret_cast<f32x4*>(sp)      = a0;
            *reinterpret_cast<f32x4*>(sp + 4)  = a1;
            *reinterpret_cast<f32x4*>(sp + 8)  = a2;
            *reinterpret_cast<f32x4*>(sp + 12) = a3;
        }
        __syncthreads();               // s_s ready

        // (c) prefetch next grp's q while pos path runs
        if (grp == 0)
            qreg = *reinterpret_cast<const float4*>(
                &qbn[((size_t)b * M_ + (h0 + 1) * W_ + qm_) * 64 + qc4]);

        // 3) position path: v direct from global, double-buffered (vrC/vrN)
        float po[4][4];
#pragma unroll
        for (int ip = 0; ip < 4; ip++)
#pragma unroll
            for (int n = 0; n < 4; n++) po[ip][n] = 0.f;

        float vrC[10], vrN[10];
        {
            const int gr = h0 + grp - 3;           // dy = 0 row
            if (gr >= 0 && gr < H_) {
#pragma unroll
                for (int j = 0; j < 10; j++) {
                    const int colc = px0 - 3 + j;
                    vrC[j] = (colc >= 0 && colc < W_)
                           ? vb_b[(size_t)(gr * W_ + colc) * DV] : 0.f;
                }
            } else {
#pragma unroll
                for (int j = 0; j < 10; j++) vrC[j] = 0.f;
            }
        }
#pragma unroll 1
        for (int dy = 0; dy < 7; dy++) {
            // issue next row's loads first (covered by this row's FMAs)
            const int grn = h0 + grp - 2 + dy;     // dy+1 row
            if (dy < 6 && grn >= 0 && grn < H_) {
#pragma unroll
                for (int j = 0; j < 10; j++) {
                    const int colc = px0 - 3 + j;
                    vrN[j] = (colc >= 0 && colc < W_)
                           ? vb_b[(size_t)(grn * W_ + colc) * DV] : 0.f;
                }
            } else {
#pragma unroll
                for (int j = 0; j < 10; j++) vrN[j] = 0.f;
            }
#pragma unroll
            for (int dx = 0; dx < 7; dx++) {
                const int tap = dy * 7 + dx;
#pragma unroll
                for (int ip = 0; ip < 4; ip++) {
                    float4 s4 = *reinterpret_cast<const float4*>(
                        &s_s[(px0 + ip) * 208 + tap * 4]);
                    const float vv = vrC[ip + dx];
                    po[ip][0] = fmaf(vv, s4.x, po[ip][0]);
                    po[ip][1] = fmaf(vv, s4.y, po[ip][1]);
                    po[ip][2] = fmaf(vv, s4.z, po[ip][2]);
                    po[ip][3] = fmaf(vv, s4.w, po[ip][3]);
                }
            }
#pragma unroll
            for (int j = 0; j < 10; j++) vrC[j] = vrN[j];
        }

        // 4) epilogue: lamv hoisted (ip-invariant), content q from LDS
        float lamv[16];
#pragma unroll
        for (int k = 0; k < 16; k++)
            lamv[k] = cl_s[k * DV + vd] + lb_s[k];
#pragma unroll
        for (int ip = 0; ip < 4; ip++) {
            const int p = px0 + ip;
            float4 ov;
            float* ovp = reinterpret_cast<float*>(&ov);
#pragma unroll
            for (int n = 0; n < 4; n++) {
                const float4* q4 = reinterpret_cast<const float4*>(&qs[p][n * 16]);
                float4 qa = q4[0], qb4 = q4[1], qc = q4[2], qd = q4[3];
                ovp[n] = po[ip][n]
                       + qa.x * lamv[0] + qa.y * lamv[1] + qa.z * lamv[2] + qa.w * lamv[3]
                       + qb4.x * lamv[4] + qb4.y * lamv[5] + qb4.z * lamv[6] + qb4.w * lamv[7]
                       + qc.x * lamv[8] + qc.y * lamv[9] + qc.z * lamv[10] + qc.w * lamv[11]
                       + qd.x * lamv[12] + qd.y * lamv[13] + qd.z * lamv[14] + qd.w * lamv[15];
            }
            *reinterpret_cast<float4*>(&ostage[vd][p * 4]) = ov;
        }
        __syncthreads();
        // flush this row: 2048 float4, lanes consecutive -> coalesced
        {
            const int mrow4 = mrow * 4;
            for (int i4 = tid; i4 < 2048; i4 += 512) {
                const int vdw  = i4 >> 5;
                const int off4 = (i4 & 31) * 4;
                float4 val = *reinterpret_cast<const float4*>(&ostage[vdw][off4]);
                *reinterpret_cast<float4*>(
                    out + (size_t)b * (C_ * M_) + (size_t)vdw * 4096 + mrow4 + off4) = val;
            }
        }
        __syncthreads();
    }
}

extern "C" void kernel_launch(void* const* d_in, const int* in_sizes, int n_in,
                              void* d_out, int out_size, void* d_ws, size_t ws_size,
                              hipStream_t stream)
{
    (void)in_sizes; (void)n_in; (void)out_size; (void)ws_size;
    const float* x   = (const float*)d_in[0];
    const float* w   = (const float*)d_in[1];
    const float* qg  = (const float*)d_in[2];
    const float* qb  = (const float*)d_in[3];
    const float* qm  = (const float*)d_in[4];
    const float* qvr = (const float*)d_in[5];
    const float* vg  = (const float*)d_in[6];
    const float* vb  = (const float*)d_in[7];
    const float* vm  = (const float*)d_in[8];
    const float* vvr = (const float*)d_in[9];
    const float* lw  = (const float*)d_in[10];
    const float* lb  = (const float*)d_in[11];
    float* out = (float*)d_out;

    float* ws   = (float*)d_ws;
    float* q_bn = ws;                        // [b][m][n][k]  2,097,152 f
    float* v_bn = ws + 2097152;              // [b][m][vd]    2,097,152 f
    float* k_bf = ws + 4194304;              // [b][k][m]       524,288 f
    float* clam = ws + 4718592;              // [b][k][vd]       32,768 f
    __bf16* wbf = (__bf16*)(ws + 4751360);   // 36,864 bf16

    hipMemsetAsync(clam, 0, 32768 * sizeof(float), stream);
    hipLaunchKernelGGL(k_wbf, dim3(36), dim3(256), 0, stream, w, wbf);
    hipLaunchKernelGGL(k_qkv, dim3(512), dim3(256), 0, stream,
                       x, wbf, qg, qb, qm, qvr, vg, vb, vm, vvr, q_bn, k_bf, v_bn);
    hipLaunchKernelGGL(k_softmax, dim3(512), dim3(256), 0, stream, k_bf);
    hipLaunchKernelGGL(k_clam, dim3(512), dim3(256), 0, stream, k_bf, v_bn, clam);
    hipLaunchKernelGGL(k_fuse, dim3(512), dim3(512), 0, stream,
                       v_bn, q_bn, clam, lw, lb, out);
}

// Round 23
// 89.650 us; speedup vs baseline: 1.0683x; 1.0162x over previous
//
#include <hip/hip_runtime.h>
#include <hip/hip_bf16.h>

constexpr int B_ = 32, C_ = 256, H_ = 32, W_ = 32, M_ = 1024;
constexpr int NH = 4, DK = 16, DV = 64;
constexpr float EPS = 1e-5f;

using bf16x8 = __bf16 __attribute__((ext_vector_type(8)));
using f32x4  = float __attribute__((ext_vector_type(4)));

struct alignas(8) Bf4 { __bf16 a, b, c, d; };

// ---------------- Kernel 1: qkv = W @ x via bf16 MFMA, + BN ----------------
// r23: W staged bf16 in LDS per chunk (converted ONCE per chunk during
// staging, off the MFMA critical path -- unlike r19's per-MFMA cvt).
// k_wbf kernel + wbf workspace + one launch gap deleted.  A-frags now
// ds_read_b128 (2-way bank alias = free); B path unchanged.
__global__ __launch_bounds__(256) void k_qkv(
    const float* __restrict__ x, const float* __restrict__ w,
    const float* __restrict__ qg, const float* __restrict__ qb,
    const float* __restrict__ qm, const float* __restrict__ qv,
    const float* __restrict__ vg, const float* __restrict__ vb,
    const float* __restrict__ vm, const float* __restrict__ vv,
    float* __restrict__ q_out, float* __restrict__ k_out,
    float* __restrict__ v_out)
{
    __shared__ __bf16 xT[64 * 72];                  // 9 KB
    __shared__ __bf16 wsb[144 * 72];                // 20.25 KB (bf16 W chunk)
    __shared__ __align__(16) float ostage[64 * 68]; // 17 KB (reused per pass)
    __shared__ __align__(16) float inv_s[144];
    __shared__ __align__(16) float add_s[144];

    const int b    = blockIdx.x >> 4;
    const int m0   = (blockIdx.x & 15) * 64;
    const int tid  = threadIdx.x;
    const int wv   = tid >> 6;
    const int lane = tid & 63;
    const int col  = lane & 15;
    const int rowg = lane >> 4;

    if (tid < 144) {
        float iv = 1.f, ad = 0.f;
        if (tid < 64)       { iv = qg[tid] * rsqrtf(qv[tid] + EPS); ad = qb[tid] - qm[tid] * iv; }
        else if (tid >= 80) { int d = tid - 80; iv = vg[d] * rsqrtf(vv[d] + EPS); ad = vb[d] - vm[d] * iv; }
        inv_s[tid] = iv; add_s[tid] = ad;
    }

    f32x4 acc[9];
#pragma unroll
    for (int j = 0; j < 9; j++) acc[j] = (f32x4){0.f, 0.f, 0.f, 0.f};

    for (int c0 = 0; c0 < C_; c0 += 64) {
        __syncthreads();
        // stage x tile: xT[m][c] bf16 (transposed + cvt), coalesced per c
#pragma unroll
        for (int i = 0; i < 4; i++) {
            int flat = tid + 256 * i;
            int m = flat & 63, c4 = flat >> 6;
            const float* xp = &x[((size_t)b * C_ + c0 + c4 * 4) * M_ + m0 + m];
            float f0 = xp[0], f1 = xp[M_], f2 = xp[2 * M_], f3 = xp[3 * M_];
            Bf4 o{(__bf16)f0, (__bf16)f1, (__bf16)f2, (__bf16)f3};
            *reinterpret_cast<Bf4*>(&xT[m * 72 + c4 * 4]) = o;
        }
        // stage W chunk: wsb[o][c] bf16, 2304 Bf4 = 9/thread, coalesced rows
#pragma unroll
        for (int i = 0; i < 9; i++) {
            int f4 = tid + 256 * i;                // 0..2303
            int o = f4 >> 4, cf = (f4 & 15) * 4;
            float4 wv4 = *reinterpret_cast<const float4*>(&w[o * C_ + c0 + cf]);
            Bf4 ob{(__bf16)wv4.x, (__bf16)wv4.y, (__bf16)wv4.z, (__bf16)wv4.w};
            *reinterpret_cast<Bf4*>(&wsb[o * 72 + cf]) = ob;
        }
        __syncthreads();
#pragma unroll
        for (int ks = 0; ks < 2; ks++) {
            const int cl = ks * 32 + rowg * 8;
            bf16x8 bf = *reinterpret_cast<const bf16x8*>(
                &xT[(16 * wv + col) * 72 + cl]);
#pragma unroll
            for (int j = 0; j < 9; j++) {
                bf16x8 af = *reinterpret_cast<const bf16x8*>(
                    &wsb[(16 * j + col) * 72 + cl]);
                acc[j] = __builtin_amdgcn_mfma_f32_16x16x32_bf16(af, bf, acc[j], 0, 0, 0);
            }
        }
    }

    const int mloc = 16 * wv + col;

    __syncthreads();
#pragma unroll
    for (int j = 0; j < 4; j++)
        *reinterpret_cast<f32x4*>(&ostage[mloc * 68 + 16 * j + rowg * 4]) = acc[j];
    __syncthreads();
#pragma unroll
    for (int i = 0; i < 4; i++) {
        int fl = tid + 256 * i;
        int m = fl >> 4, oc4 = (fl & 15) * 4;
        float4 vr = *reinterpret_cast<const float4*>(&ostage[m * 68 + oc4]);
        float4 iv = *reinterpret_cast<const float4*>(&inv_s[oc4]);
        float4 ad = *reinterpret_cast<const float4*>(&add_s[oc4]);
        float4 rs{vr.x * iv.x + ad.x, vr.y * iv.y + ad.y,
                  vr.z * iv.z + ad.z, vr.w * iv.w + ad.w};
        *reinterpret_cast<float4*>(&q_out[((size_t)b * M_ + m0 + m) * 64 + oc4]) = rs;
    }

    __syncthreads();
#pragma unroll
    for (int r = 0; r < 4; r++)
        ostage[(rowg * 4 + r) * 68 + mloc] = acc[4][r];
    __syncthreads();
    {
        int kk = tid >> 4, m4 = (tid & 15) * 4;
        float4 vr = *reinterpret_cast<const float4*>(&ostage[kk * 68 + m4]);
        *reinterpret_cast<float4*>(&k_out[((size_t)b * DK + kk) * M_ + m0 + m4]) = vr;
    }

    __syncthreads();
#pragma unroll
    for (int j = 5; j < 9; j++)
        *reinterpret_cast<f32x4*>(&ostage[mloc * 68 + 16 * (j - 5) + rowg * 4]) = acc[j];
    __syncthreads();
#pragma unroll
    for (int i = 0; i < 4; i++) {
        int fl = tid + 256 * i;
        int m = fl >> 4, oc4 = (fl & 15) * 4;
        float4 vr = *reinterpret_cast<const float4*>(&ostage[m * 68 + oc4]);
        float4 iv = *reinterpret_cast<const float4*>(&inv_s[80 + oc4]);
        float4 ad = *reinterpret_cast<const float4*>(&add_s[80 + oc4]);
        float4 rs{vr.x * iv.x + ad.x, vr.y * iv.y + ad.y,
                  vr.z * iv.z + ad.z, vr.w * iv.w + ad.w};
        *reinterpret_cast<float4*>(&v_out[((size_t)b * M_ + m0 + m) * 64 + oc4]) = rs;
    }
}

// ---------------- Kernel 2: softmax over M per (b,k) row, in place ---------
// (r17 float4 version, proven)
__global__ __launch_bounds__(256) void k_softmax(float* __restrict__ kl)
{
    float4* p4 = reinterpret_cast<float4*>(kl + (size_t)blockIdx.x * M_);
    const int tid = threadIdx.x;
    float4 v = p4[tid];
    float mx = fmaxf(fmaxf(v.x, v.y), fmaxf(v.z, v.w));
#pragma unroll
    for (int off = 32; off >= 1; off >>= 1) mx = fmaxf(mx, __shfl_xor(mx, off));
    __shared__ float red[8];
    if ((tid & 63) == 0) red[tid >> 6] = mx;
    __syncthreads();
    mx = fmaxf(fmaxf(red[0], red[1]), fmaxf(red[2], red[3]));
    v.x = __expf(v.x - mx); v.y = __expf(v.y - mx);
    v.z = __expf(v.z - mx); v.w = __expf(v.w - mx);
    float s = v.x + v.y + v.z + v.w;
#pragma unroll
    for (int off = 32; off >= 1; off >>= 1) s += __shfl_xor(s, off);
    if ((tid & 63) == 0) red[4 + (tid >> 6)] = s;
    __syncthreads();
    s = red[4] + red[5] + red[6] + red[7];
    float inv = 1.f / s;
    v.x *= inv; v.y *= inv; v.z *= inv; v.w *= inv;
    p4[tid] = v;
}

// ---------------- Kernel 3: content_lam[b,k,vd] = sum_m ksm * v ------------
// (r17 grid-512 version, proven)
__global__ __launch_bounds__(256) void k_clam(
    const float* __restrict__ ksm, const float* __restrict__ vbn,
    float* __restrict__ clam)
{
    const int b   = blockIdx.x >> 4;
    const int m0  = (blockIdx.x & 15) * 64;
    const int tid = threadIdx.x;
    const int vd  = tid & 63;
    const int kq  = tid >> 6;
    float acc[4] = {0.f, 0.f, 0.f, 0.f};
    for (int mi = 0; mi < 64; mi++) {
        const int m = m0 + mi;
        const float vvv = vbn[(b * M_ + m) * DV + vd];
#pragma unroll
        for (int j = 0; j < 4; j++)
            acc[j] = fmaf(ksm[(b * DK + kq + 4 * j) * M_ + m], vvv, acc[j]);
    }
#pragma unroll
    for (int j = 0; j < 4; j++)
        atomicAdd(&clam[(b * DK + kq + 4 * j) * DV + vd], acc[j]);
}

// ---------------- Kernel 4: fused s-compute + pos + content ----------------
// (round-16 version, byte-identical: proven 48.4-48.6 us; frozen)
__global__ __launch_bounds__(512) void k_fuse(
    const float* __restrict__ vbn, const float* __restrict__ qbn,
    const float* __restrict__ clam, const float* __restrict__ lw,
    const float* __restrict__ lb, float* __restrict__ out)
{
    __shared__ float qs[32][68];           // 8.7 KB
    __shared__ float lws[16 * 52];         // 3.3 KB (taps 49..51 = 0)
    __shared__ float s_s[32 * 208];        // 26.6 KB  [px][tap*4+n]
    __shared__ float ostage[64][132];      // 33.8 KB
    __shared__ float cl_s[16 * 64];        // 4 KB
    __shared__ float lb_s[16];

    const int b   = blockIdx.x >> 4;
    const int rt  = blockIdx.x & 15;
    const int h0  = rt * 2;
    const int tid = threadIdx.x;

    for (int i = tid; i < 832; i += 512) {
        int k = i / 52, t = i % 52;
        lws[i] = (t < 49) ? lw[k * 49 + t] : 0.f;
    }
    if (tid < 256)
        *reinterpret_cast<float4*>(&cl_s[tid * 4]) =
            *reinterpret_cast<const float4*>(&clam[b * DK * DV + tid * 4]);
    if (tid < 16) lb_s[tid] = lb[tid];

    const int vd  = tid & 63;
    const int pg  = tid >> 6;
    const int px0 = pg * 4;
    const float* vb_b = vbn + (size_t)b * M_ * DV + vd;

    const int qm_ = tid >> 4, qc4 = (tid & 15) * 4;   // q staging coords
    float4 qreg = *reinterpret_cast<const float4*>(
        &qbn[((size_t)b * M_ + h0 * W_ + qm_) * 64 + qc4]);

    for (int grp = 0; grp < 2; grp++) {
        const int mrow = (h0 + grp) * W_;
        // 1) write prefetched q row tile
        *reinterpret_cast<float4*>(&qs[qm_][qc4]) = qreg;
        __syncthreads();               // qs (and lws/cl_s on iter 0) ready

        // 2) s_s[m][t][n] = sum_k qs[m][n*16+k] * lws[k][t]
        if (tid < 416) {
            const int m  = tid / 13;
            const int t4 = (tid % 13) * 4;
            f32x4 a0 = {0.f,0.f,0.f,0.f}, a1 = a0, a2 = a0, a3 = a0;
#pragma unroll
            for (int k = 0; k < 16; k++) {
                float4 lw4 = *reinterpret_cast<const float4*>(&lws[k * 52 + t4]);
                float q0 = qs[m][k],      q1 = qs[m][16 + k];
                float q2 = qs[m][32 + k], q3 = qs[m][48 + k];
                a0[0] = fmaf(q0, lw4.x, a0[0]); a0[1] = fmaf(q1, lw4.x, a0[1]);
                a0[2] = fmaf(q2, lw4.x, a0[2]); a0[3] = fmaf(q3, lw4.x, a0[3]);
                a1[0] = fmaf(q0, lw4.y, a1[0]); a1[1] = fmaf(q1, lw4.y, a1[1]);
                a1[2] = fmaf(q2, lw4.y, a1[2]); a1[3] = fmaf(q3, lw4.y, a1[3]);
                a2[0] = fmaf(q0, lw4.z, a2[0]); a2[1] = fmaf(q1, lw4.z, a2[1]);
                a2[2] = fmaf(q2, lw4.z, a2[2]); a2[3] = fmaf(q3, lw4.z, a2[3]);
                a3[0] = fmaf(q0, lw4.w, a3[0]); a3[1] = fmaf(q1, lw4.w, a3[1]);
                a3[2] = fmaf(q2, lw4.w, a3[2]); a3[3] = fmaf(q3, lw4.w, a3[3]);
            }
            float* sp = &s_s[m * 208 + t4 * 4];
            *reinterpret_cast<f32x4*>(sp)      = a0;
            *reinterpret_cast<f32x4*>(sp + 4)  = a1;
            *reinterpret_cast<f32x4*>(sp + 8)  = a2;
            *reinterpret_cast<f32x4*>(sp + 12) = a3;
        }
        __syncthreads();               // s_s ready

        // (c) prefetch next grp's q while pos path runs
        if (grp == 0)
            qreg = *reinterpret_cast<const float4*>(
                &qbn[((size_t)b * M_ + (h0 + 1) * W_ + qm_) * 64 + qc4]);

        // 3) position path: v direct from global, double-buffered (vrC/vrN)
        float po[4][4];
#pragma unroll
        for (int ip = 0; ip < 4; ip++)
#pragma unroll
            for (int n = 0; n < 4; n++) po[ip][n] = 0.f;

        float vrC[10], vrN[10];
        {
            const int gr = h0 + grp - 3;           // dy = 0 row
            if (gr >= 0 && gr < H_) {
#pragma unroll
                for (int j = 0; j < 10; j++) {
                    const int colc = px0 - 3 + j;
                    vrC[j] = (colc >= 0 && colc < W_)
                           ? vb_b[(size_t)(gr * W_ + colc) * DV] : 0.f;
                }
            } else {
#pragma unroll
                for (int j = 0; j < 10; j++) vrC[j] = 0.f;
            }
        }
#pragma unroll 1
        for (int dy = 0; dy < 7; dy++) {
            // issue next row's loads first (covered by this row's FMAs)
            const int grn = h0 + grp - 2 + dy;     // dy+1 row
            if (dy < 6 && grn >= 0 && grn < H_) {
#pragma unroll
                for (int j = 0; j < 10; j++) {
                    const int colc = px0 - 3 + j;
                    vrN[j] = (colc >= 0 && colc < W_)
                           ? vb_b[(size_t)(grn * W_ + colc) * DV] : 0.f;
                }
            } else {
#pragma unroll
                for (int j = 0; j < 10; j++) vrN[j] = 0.f;
            }
#pragma unroll
            for (int dx = 0; dx < 7; dx++) {
                const int tap = dy * 7 + dx;
#pragma unroll
                for (int ip = 0; ip < 4; ip++) {
                    float4 s4 = *reinterpret_cast<const float4*>(
                        &s_s[(px0 + ip) * 208 + tap * 4]);
                    const float vv = vrC[ip + dx];
                    po[ip][0] = fmaf(vv, s4.x, po[ip][0]);
                    po[ip][1] = fmaf(vv, s4.y, po[ip][1]);
                    po[ip][2] = fmaf(vv, s4.z, po[ip][2]);
                    po[ip][3] = fmaf(vv, s4.w, po[ip][3]);
                }
            }
#pragma unroll
            for (int j = 0; j < 10; j++) vrC[j] = vrN[j];
        }

        // 4) epilogue: lamv hoisted (ip-invariant), content q from LDS
        float lamv[16];
#pragma unroll
        for (int k = 0; k < 16; k++)
            lamv[k] = cl_s[k * DV + vd] + lb_s[k];
#pragma unroll
        for (int ip = 0; ip < 4; ip++) {
            const int p = px0 + ip;
            float4 ov;
            float* ovp = reinterpret_cast<float*>(&ov);
#pragma unroll
            for (int n = 0; n < 4; n++) {
                const float4* q4 = reinterpret_cast<const float4*>(&qs[p][n * 16]);
                float4 qa = q4[0], qb4 = q4[1], qc = q4[2], qd = q4[3];
                ovp[n] = po[ip][n]
                       + qa.x * lamv[0] + qa.y * lamv[1] + qa.z * lamv[2] + qa.w * lamv[3]
                       + qb4.x * lamv[4] + qb4.y * lamv[5] + qb4.z * lamv[6] + qb4.w * lamv[7]
                       + qc.x * lamv[8] + qc.y * lamv[9] + qc.z * lamv[10] + qc.w * lamv[11]
                       + qd.x * lamv[12] + qd.y * lamv[13] + qd.z * lamv[14] + qd.w * lamv[15];
            }
            *reinterpret_cast<float4*>(&ostage[vd][p * 4]) = ov;
        }
        __syncthreads();
        // flush this row: 2048 float4, lanes consecutive -> coalesced
        {
            const int mrow4 = mrow * 4;
            for (int i4 = tid; i4 < 2048; i4 += 512) {
                const int vdw  = i4 >> 5;
                const int off4 = (i4 & 31) * 4;
                float4 val = *reinterpret_cast<const float4*>(&ostage[vdw][off4]);
                *reinterpret_cast<float4*>(
                    out + (size_t)b * (C_ * M_) + (size_t)vdw * 4096 + mrow4 + off4) = val;
            }
        }
        __syncthreads();
    }
}

extern "C" void kernel_launch(void* const* d_in, const int* in_sizes, int n_in,
                              void* d_out, int out_size, void* d_ws, size_t ws_size,
                              hipStream_t stream)
{
    (void)in_sizes; (void)n_in; (void)out_size; (void)ws_size;
    const float* x   = (const float*)d_in[0];
    const float* w   = (const float*)d_in[1];
    const float* qg  = (const float*)d_in[2];
    const float* qb  = (const float*)d_in[3];
    const float* qm  = (const float*)d_in[4];
    const float* qvr = (const float*)d_in[5];
    const float* vg  = (const float*)d_in[6];
    const float* vb  = (const float*)d_in[7];
    const float* vm  = (const float*)d_in[8];
    const float* vvr = (const float*)d_in[9];
    const float* lw  = (const float*)d_in[10];
    const float* lb  = (const float*)d_in[11];
    float* out = (float*)d_out;

    float* ws   = (float*)d_ws;
    float* q_bn = ws;                        // [b][m][n][k]  2,097,152 f
    float* v_bn = ws + 2097152;              // [b][m][vd]    2,097,152 f
    float* k_bf = ws + 4194304;              // [b][k][m]       524,288 f
    float* clam = ws + 4718592;              // [b][k][vd]       32,768 f

    hipMemsetAsync(clam, 0, 32768 * sizeof(float), stream);
    hipLaunchKernelGGL(k_qkv, dim3(512), dim3(256), 0, stream,
                       x, w, qg, qb, qm, qvr, vg, vb, vm, vvr, q_bn, k_bf, v_bn);
    hipLaunchKernelGGL(k_softmax, dim3(512), dim3(256), 0, stream, k_bf);
    hipLaunchKernelGGL(k_clam, dim3(512), dim3(256), 0, stream, k_bf, v_bn, clam);
    hipLaunchKernelGGL(k_fuse, dim3(512), dim3(512), 0, stream,
                       v_bn, q_bn, clam, lw, lb, out);
}

// Round 24
// 84.181 us; speedup vs baseline: 1.1377x; 1.0650x over previous
//
#include <hip/hip_runtime.h>
#include <hip/hip_bf16.h>

constexpr int B_ = 32, C_ = 256, H_ = 32, W_ = 32, M_ = 1024;
constexpr int NH = 4, DK = 16, DV = 64;
constexpr float EPS = 1e-5f;

using bf16x8 = __bf16 __attribute__((ext_vector_type(8)));
using f32x4  = float __attribute__((ext_vector_type(4)));

struct alignas(8) Bf4 { __bf16 a, b, c, d; };

// ---------------- Kernel 1: qkv = W @ x via bf16 MFMA, + BN ----------------
// (r23 version + r24 delta: clam zeroing folded in -- each of 512 blocks
//  zeroes 16 float4 = 64 floats; memset dispatch deleted.  Safe: k_clam
//  launches after k_qkv completes on the stream.)
__global__ __launch_bounds__(256) void k_qkv(
    const float* __restrict__ x, const float* __restrict__ w,
    const float* __restrict__ qg, const float* __restrict__ qb,
    const float* __restrict__ qm, const float* __restrict__ qv,
    const float* __restrict__ vg, const float* __restrict__ vb,
    const float* __restrict__ vm, const float* __restrict__ vv,
    float* __restrict__ q_out, float* __restrict__ k_out,
    float* __restrict__ v_out, float* __restrict__ clam_z)
{
    __shared__ __bf16 xT[64 * 72];                  // 9 KB
    __shared__ __bf16 wsb[144 * 72];                // 20.25 KB (bf16 W chunk)
    __shared__ __align__(16) float ostage[64 * 68]; // 17 KB (reused per pass)
    __shared__ __align__(16) float inv_s[144];
    __shared__ __align__(16) float add_s[144];

    const int b    = blockIdx.x >> 4;
    const int m0   = (blockIdx.x & 15) * 64;
    const int tid  = threadIdx.x;
    const int wv   = tid >> 6;
    const int lane = tid & 63;
    const int col  = lane & 15;
    const int rowg = lane >> 4;

    // r24: zero this block's 64-float slice of clam (replaces hipMemsetAsync)
    if (tid < 16)
        *reinterpret_cast<float4*>(&clam_z[blockIdx.x * 64 + tid * 4]) =
            make_float4(0.f, 0.f, 0.f, 0.f);

    if (tid < 144) {
        float iv = 1.f, ad = 0.f;
        if (tid < 64)       { iv = qg[tid] * rsqrtf(qv[tid] + EPS); ad = qb[tid] - qm[tid] * iv; }
        else if (tid >= 80) { int d = tid - 80; iv = vg[d] * rsqrtf(vv[d] + EPS); ad = vb[d] - vm[d] * iv; }
        inv_s[tid] = iv; add_s[tid] = ad;
    }

    f32x4 acc[9];
#pragma unroll
    for (int j = 0; j < 9; j++) acc[j] = (f32x4){0.f, 0.f, 0.f, 0.f};

    for (int c0 = 0; c0 < C_; c0 += 64) {
        __syncthreads();
        // stage x tile: xT[m][c] bf16 (transposed + cvt), coalesced per c
#pragma unroll
        for (int i = 0; i < 4; i++) {
            int flat = tid + 256 * i;
            int m = flat & 63, c4 = flat >> 6;
            const float* xp = &x[((size_t)b * C_ + c0 + c4 * 4) * M_ + m0 + m];
            float f0 = xp[0], f1 = xp[M_], f2 = xp[2 * M_], f3 = xp[3 * M_];
            Bf4 o{(__bf16)f0, (__bf16)f1, (__bf16)f2, (__bf16)f3};
            *reinterpret_cast<Bf4*>(&xT[m * 72 + c4 * 4]) = o;
        }
        // stage W chunk: wsb[o][c] bf16, 2304 Bf4 = 9/thread, coalesced rows
#pragma unroll
        for (int i = 0; i < 9; i++) {
            int f4 = tid + 256 * i;                // 0..2303
            int o = f4 >> 4, cf = (f4 & 15) * 4;
            float4 wv4 = *reinterpret_cast<const float4*>(&w[o * C_ + c0 + cf]);
            Bf4 ob{(__bf16)wv4.x, (__bf16)wv4.y, (__bf16)wv4.z, (__bf16)wv4.w};
            *reinterpret_cast<Bf4*>(&wsb[o * 72 + cf]) = ob;
        }
        __syncthreads();
#pragma unroll
        for (int ks = 0; ks < 2; ks++) {
            const int cl = ks * 32 + rowg * 8;
            bf16x8 bf = *reinterpret_cast<const bf16x8*>(
                &xT[(16 * wv + col) * 72 + cl]);
#pragma unroll
            for (int j = 0; j < 9; j++) {
                bf16x8 af = *reinterpret_cast<const bf16x8*>(
                    &wsb[(16 * j + col) * 72 + cl]);
                acc[j] = __builtin_amdgcn_mfma_f32_16x16x32_bf16(af, bf, acc[j], 0, 0, 0);
            }
        }
    }

    const int mloc = 16 * wv + col;

    __syncthreads();
#pragma unroll
    for (int j = 0; j < 4; j++)
        *reinterpret_cast<f32x4*>(&ostage[mloc * 68 + 16 * j + rowg * 4]) = acc[j];
    __syncthreads();
#pragma unroll
    for (int i = 0; i < 4; i++) {
        int fl = tid + 256 * i;
        int m = fl >> 4, oc4 = (fl & 15) * 4;
        float4 vr = *reinterpret_cast<const float4*>(&ostage[m * 68 + oc4]);
        float4 iv = *reinterpret_cast<const float4*>(&inv_s[oc4]);
        float4 ad = *reinterpret_cast<const float4*>(&add_s[oc4]);
        float4 rs{vr.x * iv.x + ad.x, vr.y * iv.y + ad.y,
                  vr.z * iv.z + ad.z, vr.w * iv.w + ad.w};
        *reinterpret_cast<float4*>(&q_out[((size_t)b * M_ + m0 + m) * 64 + oc4]) = rs;
    }

    __syncthreads();
#pragma unroll
    for (int r = 0; r < 4; r++)
        ostage[(rowg * 4 + r) * 68 + mloc] = acc[4][r];
    __syncthreads();
    {
        int kk = tid >> 4, m4 = (tid & 15) * 4;
        float4 vr = *reinterpret_cast<const float4*>(&ostage[kk * 68 + m4]);
        *reinterpret_cast<float4*>(&k_out[((size_t)b * DK + kk) * M_ + m0 + m4]) = vr;
    }

    __syncthreads();
#pragma unroll
    for (int j = 5; j < 9; j++)
        *reinterpret_cast<f32x4*>(&ostage[mloc * 68 + 16 * (j - 5) + rowg * 4]) = acc[j];
    __syncthreads();
#pragma unroll
    for (int i = 0; i < 4; i++) {
        int fl = tid + 256 * i;
        int m = fl >> 4, oc4 = (fl & 15) * 4;
        float4 vr = *reinterpret_cast<const float4*>(&ostage[m * 68 + oc4]);
        float4 iv = *reinterpret_cast<const float4*>(&inv_s[80 + oc4]);
        float4 ad = *reinterpret_cast<const float4*>(&add_s[80 + oc4]);
        float4 rs{vr.x * iv.x + ad.x, vr.y * iv.y + ad.y,
                  vr.z * iv.z + ad.z, vr.w * iv.w + ad.w};
        *reinterpret_cast<float4*>(&v_out[((size_t)b * M_ + m0 + m) * 64 + oc4]) = rs;
    }
}

// ---------------- Kernel 2: softmax over M per (b,k) row, in place ---------
// (r17 float4 version, proven)
__global__ __launch_bounds__(256) void k_softmax(float* __restrict__ kl)
{
    float4* p4 = reinterpret_cast<float4*>(kl + (size_t)blockIdx.x * M_);
    const int tid = threadIdx.x;
    float4 v = p4[tid];
    float mx = fmaxf(fmaxf(v.x, v.y), fmaxf(v.z, v.w));
#pragma unroll
    for (int off = 32; off >= 1; off >>= 1) mx = fmaxf(mx, __shfl_xor(mx, off));
    __shared__ float red[8];
    if ((tid & 63) == 0) red[tid >> 6] = mx;
    __syncthreads();
    mx = fmaxf(fmaxf(red[0], red[1]), fmaxf(red[2], red[3]));
    v.x = __expf(v.x - mx); v.y = __expf(v.y - mx);
    v.z = __expf(v.z - mx); v.w = __expf(v.w - mx);
    float s = v.x + v.y + v.z + v.w;
#pragma unroll
    for (int off = 32; off >= 1; off >>= 1) s += __shfl_xor(s, off);
    if ((tid & 63) == 0) red[4 + (tid >> 6)] = s;
    __syncthreads();
    s = red[4] + red[5] + red[6] + red[7];
    float inv = 1.f / s;
    v.x *= inv; v.y *= inv; v.z *= inv; v.w *= inv;
    p4[tid] = v;
}

// ---------------- Kernel 3: content_lam[b,k,vd] = sum_m ksm * v ------------
// (r17 grid-512 version, proven)
__global__ __launch_bounds__(256) void k_clam(
    const float* __restrict__ ksm, const float* __restrict__ vbn,
    float* __restrict__ clam)
{
    const int b   = blockIdx.x >> 4;
    const int m0  = (blockIdx.x & 15) * 64;
    const int tid = threadIdx.x;
    const int vd  = tid & 63;
    const int kq  = tid >> 6;
    float acc[4] = {0.f, 0.f, 0.f, 0.f};
    for (int mi = 0; mi < 64; mi++) {
        const int m = m0 + mi;
        const float vvv = vbn[(b * M_ + m) * DV + vd];
#pragma unroll
        for (int j = 0; j < 4; j++)
            acc[j] = fmaf(ksm[(b * DK + kq + 4 * j) * M_ + m], vvv, acc[j]);
    }
#pragma unroll
    for (int j = 0; j < 4; j++)
        atomicAdd(&clam[(b * DK + kq + 4 * j) * DV + vd], acc[j]);
}

// ---------------- Kernel 4: fused s-compute + pos + content ----------------
// (round-16 version, byte-identical: proven 48.4-48.6 us; frozen)
__global__ __launch_bounds__(512) void k_fuse(
    const float* __restrict__ vbn, const float* __restrict__ qbn,
    const float* __restrict__ clam, const float* __restrict__ lw,
    const float* __restrict__ lb, float* __restrict__ out)
{
    __shared__ float qs[32][68];           // 8.7 KB
    __shared__ float lws[16 * 52];         // 3.3 KB (taps 49..51 = 0)
    __shared__ float s_s[32 * 208];        // 26.6 KB  [px][tap*4+n]
    __shared__ float ostage[64][132];      // 33.8 KB
    __shared__ float cl_s[16 * 64];        // 4 KB
    __shared__ float lb_s[16];

    const int b   = blockIdx.x >> 4;
    const int rt  = blockIdx.x & 15;
    const int h0  = rt * 2;
    const int tid = threadIdx.x;

    for (int i = tid; i < 832; i += 512) {
        int k = i / 52, t = i % 52;
        lws[i] = (t < 49) ? lw[k * 49 + t] : 0.f;
    }
    if (tid < 256)
        *reinterpret_cast<float4*>(&cl_s[tid * 4]) =
            *reinterpret_cast<const float4*>(&clam[b * DK * DV + tid * 4]);
    if (tid < 16) lb_s[tid] = lb[tid];

    const int vd  = tid & 63;
    const int pg  = tid >> 6;
    const int px0 = pg * 4;
    const float* vb_b = vbn + (size_t)b * M_ * DV + vd;

    const int qm_ = tid >> 4, qc4 = (tid & 15) * 4;   // q staging coords
    float4 qreg = *reinterpret_cast<const float4*>(
        &qbn[((size_t)b * M_ + h0 * W_ + qm_) * 64 + qc4]);

    for (int grp = 0; grp < 2; grp++) {
        const int mrow = (h0 + grp) * W_;
        // 1) write prefetched q row tile
        *reinterpret_cast<float4*>(&qs[qm_][qc4]) = qreg;
        __syncthreads();               // qs (and lws/cl_s on iter 0) ready

        // 2) s_s[m][t][n] = sum_k qs[m][n*16+k] * lws[k][t]
        if (tid < 416) {
            const int m  = tid / 13;
            const int t4 = (tid % 13) * 4;
            f32x4 a0 = {0.f,0.f,0.f,0.f}, a1 = a0, a2 = a0, a3 = a0;
#pragma unroll
            for (int k = 0; k < 16; k++) {
                float4 lw4 = *reinterpret_cast<const float4*>(&lws[k * 52 + t4]);
                float q0 = qs[m][k],      q1 = qs[m][16 + k];
                float q2 = qs[m][32 + k], q3 = qs[m][48 + k];
                a0[0] = fmaf(q0, lw4.x, a0[0]); a0[1] = fmaf(q1, lw4.x, a0[1]);
                a0[2] = fmaf(q2, lw4.x, a0[2]); a0[3] = fmaf(q3, lw4.x, a0[3]);
                a1[0] = fmaf(q0, lw4.y, a1[0]); a1[1] = fmaf(q1, lw4.y, a1[1]);
                a1[2] = fmaf(q2, lw4.y, a1[2]); a1[3] = fmaf(q3, lw4.y, a1[3]);
                a2[0] = fmaf(q0, lw4.z, a2[0]); a2[1] = fmaf(q1, lw4.z, a2[1]);
                a2[2] = fmaf(q2, lw4.z, a2[2]); a2[3] = fmaf(q3, lw4.z, a2[3]);
                a3[0] = fmaf(q0, lw4.w, a3[0]); a3[1] = fmaf(q1, lw4.w, a3[1]);
                a3[2] = fmaf(q2, lw4.w, a3[2]); a3[3] = fmaf(q3, lw4.w, a3[3]);
            }
            float* sp = &s_s[m * 208 + t4 * 4];
            *reinterpret_cast<f32x4*>(sp)      = a0;
            *reinterpret_cast<f32x4*>(sp + 4)  = a1;
            *reinterpret_cast<f32x4*>(sp + 8)  = a2;
            *reinterpret_cast<f32x4*>(sp + 12) = a3;
        }
        __syncthreads();               // s_s ready

        // (c) prefetch next grp's q while pos path runs
        if (grp == 0)
            qreg = *reinterpret_cast<const float4*>(
                &qbn[((size_t)b * M_ + (h0 + 1) * W_ + qm_) * 64 + qc4]);

        // 3) position path: v direct from global, double-buffered (vrC/vrN)
        float po[4][4];
#pragma unroll
        for (int ip = 0; ip < 4; ip++)
#pragma unroll
            for (int n = 0; n < 4; n++) po[ip][n] = 0.f;

        float vrC[10], vrN[10];
        {
            const int gr = h0 + grp - 3;           // dy = 0 row
            if (gr >= 0 && gr < H_) {
#pragma unroll
                for (int j = 0; j < 10; j++) {
                    const int colc = px0 - 3 + j;
                    vrC[j] = (colc >= 0 && colc < W_)
                           ? vb_b[(size_t)(gr * W_ + colc) * DV] : 0.f;
                }
            } else {
#pragma unroll
                for (int j = 0; j < 10; j++) vrC[j] = 0.f;
            }
        }
#pragma unroll 1
        for (int dy = 0; dy < 7; dy++) {
            // issue next row's loads first (covered by this row's FMAs)
            const int grn = h0 + grp - 2 + dy;     // dy+1 row
            if (dy < 6 && grn >= 0 && grn < H_) {
#pragma unroll
                for (int j = 0; j < 10; j++) {
                    const int colc = px0 - 3 + j;
                    vrN[j] = (colc >= 0 && colc < W_)
                           ? vb_b[(size_t)(grn * W_ + colc) * DV] : 0.f;
                }
            } else {
#pragma unroll
                for (int j = 0; j < 10; j++) vrN[j] = 0.f;
            }
#pragma unroll
            for (int dx = 0; dx < 7; dx++) {
                const int tap = dy * 7 + dx;
#pragma unroll
                for (int ip = 0; ip < 4; ip++) {
                    float4 s4 = *reinterpret_cast<const float4*>(
                        &s_s[(px0 + ip) * 208 + tap * 4]);
                    const float vv = vrC[ip + dx];
                    po[ip][0] = fmaf(vv, s4.x, po[ip][0]);
                    po[ip][1] = fmaf(vv, s4.y, po[ip][1]);
                    po[ip][2] = fmaf(vv, s4.z, po[ip][2]);
                    po[ip][3] = fmaf(vv, s4.w, po[ip][3]);
                }
            }
#pragma unroll
            for (int j = 0; j < 10; j++) vrC[j] = vrN[j];
        }

        // 4) epilogue: lamv hoisted (ip-invariant), content q from LDS
        float lamv[16];
#pragma unroll
        for (int k = 0; k < 16; k++)
            lamv[k] = cl_s[k * DV + vd] + lb_s[k];
#pragma unroll
        for (int ip = 0; ip < 4; ip++) {
            const int p = px0 + ip;
            float4 ov;
            float* ovp = reinterpret_cast<float*>(&ov);
#pragma unroll
            for (int n = 0; n < 4; n++) {
                const float4* q4 = reinterpret_cast<const float4*>(&qs[p][n * 16]);
                float4 qa = q4[0], qb4 = q4[1], qc = q4[2], qd = q4[3];
                ovp[n] = po[ip][n]
                       + qa.x * lamv[0] + qa.y * lamv[1] + qa.z * lamv[2] + qa.w * lamv[3]
                       + qb4.x * lamv[4] + qb4.y * lamv[5] + qb4.z * lamv[6] + qb4.w * lamv[7]
                       + qc.x * lamv[8] + qc.y * lamv[9] + qc.z * lamv[10] + qc.w * lamv[11]
                       + qd.x * lamv[12] + qd.y * lamv[13] + qd.z * lamv[14] + qd.w * lamv[15];
            }
            *reinterpret_cast<float4*>(&ostage[vd][p * 4]) = ov;
        }
        __syncthreads();
        // flush this row: 2048 float4, lanes consecutive -> coalesced
        {
            const int mrow4 = mrow * 4;
            for (int i4 = tid; i4 < 2048; i4 += 512) {
                const int vdw  = i4 >> 5;
                const int off4 = (i4 & 31) * 4;
                float4 val = *reinterpret_cast<const float4*>(&ostage[vdw][off4]);
                *reinterpret_cast<float4*>(
                    out + (size_t)b * (C_ * M_) + (size_t)vdw * 4096 + mrow4 + off4) = val;
            }
        }
        __syncthreads();
    }
}

extern "C" void kernel_launch(void* const* d_in, const int* in_sizes, int n_in,
                              void* d_out, int out_size, void* d_ws, size_t ws_size,
                              hipStream_t stream)
{
    (void)in_sizes; (void)n_in; (void)out_size; (void)ws_size;
    const float* x   = (const float*)d_in[0];
    const float* w   = (const float*)d_in[1];
    const float* qg  = (const float*)d_in[2];
    const float* qb  = (const float*)d_in[3];
    const float* qm  = (const float*)d_in[4];
    const float* qvr = (const float*)d_in[5];
    const float* vg  = (const float*)d_in[6];
    const float* vb  = (const float*)d_in[7];
    const float* vm  = (const float*)d_in[8];
    const float* vvr = (const float*)d_in[9];
    const float* lw  = (const float*)d_in[10];
    const float* lb  = (const float*)d_in[11];
    float* out = (float*)d_out;

    float* ws   = (float*)d_ws;
    float* q_bn = ws;                        // [b][m][n][k]  2,097,152 f
    float* v_bn = ws + 2097152;              // [b][m][vd]    2,097,152 f
    float* k_bf = ws + 4194304;              // [b][k][m]       524,288 f
    float* clam = ws + 4718592;              // [b][k][vd]       32,768 f

    hipLaunchKernelGGL(k_qkv, dim3(512), dim3(256), 0, stream,
                       x, w, qg, qb, qm, qvr, vg, vb, vm, vvr, q_bn, k_bf, v_bn, clam);
    hipLaunchKernelGGL(k_softmax, dim3(512), dim3(256), 0, stream, k_bf);
    hipLaunchKernelGGL(k_clam, dim3(512), dim3(256), 0, stream, k_bf, v_bn, clam);
    hipLaunchKernelGGL(k_fuse, dim3(512), dim3(512), 0, stream,
                       v_bn, q_bn, clam, lw, lb, out);
}